// Round 1
// baseline (235.255 us; speedup 1.0000x reference)
//
#include <hip/hip_runtime.h>
#include <stdint.h>

// Problem shape (fixed by reference):
#define BATCH 2
#define T_SEQ 2048
#define CDIM  1024
#define NH    16
#define HD    64
#define MROWS (BATCH*T_SEQ)   // 4096

typedef unsigned short u16;
typedef __attribute__((ext_vector_type(8))) short bf16x8;
typedef __attribute__((ext_vector_type(4))) float f32x4;
typedef __attribute__((ext_vector_type(4))) unsigned short u16x4;

__device__ __forceinline__ u16 f2b(float f) {
  union { float f; unsigned int u; } x; x.f = f;
  unsigned int r = x.u + 0x7FFFu + ((x.u >> 16) & 1u);
  return (u16)(r >> 16);
}

__device__ __forceinline__ void gload16(const void* g, void* s) {
  __builtin_amdgcn_global_load_lds(
      (const __attribute__((address_space(1))) void*)g,
      (__attribute__((address_space(3))) void*)s, 16, 0, 0);
}

// ---------------- f32 -> bf16 convert (vectorized) ----------------
__global__ __launch_bounds__(256) void cvt4(const float4* __restrict__ in,
                                            u16x4* __restrict__ out, int n4) {
  int i = blockIdx.x * 256 + threadIdx.x;
  if (i < n4) {
    float4 v = in[i];
    u16x4 o = { f2b(v.x), f2b(v.y), f2b(v.z), f2b(v.w) };
    out[i] = o;
  }
}

// ---------------- W transpose + convert: Wt[n][k] = bf16(W[k][n]) ----------------
__global__ __launch_bounds__(256) void w_trans(const float* __restrict__ W,
                                               u16* __restrict__ Wt, int C) {
  __shared__ u16 tile[64][72];
  int k0 = blockIdx.x * 64, n0 = blockIdx.y * 64;
  int tid = threadIdx.x;
  #pragma unroll
  for (int i = 0; i < 16; ++i) {
    int c = i * 256 + tid;
    int kr = c >> 6, nc = c & 63;
    tile[kr][nc] = f2b(W[(size_t)(k0 + kr) * C + n0 + nc]);
  }
  __syncthreads();
  #pragma unroll
  for (int i = 0; i < 16; ++i) {
    int c = i * 256 + tid;
    int nr = c >> 6, kc = c & 63;
    Wt[(size_t)(n0 + nr) * C + k0 + kc] = tile[kc][nr];
  }
}

// ---------------- RoPE cos/sin table ----------------
__global__ __launch_bounds__(256) void rope_tab(float* __restrict__ cosT,
                                                float* __restrict__ sinT) {
  int i = blockIdx.x * 256 + threadIdx.x;   // t*32 + j
  int t = i >> 5, j = i & 31;
  float inv = expf(-(float)j * (9.210340371976184f / 32.0f)); // 10000^(-2j/64)
  float ang = (float)t * inv;
  cosT[i] = cosf(ang);
  sinT[i] = sinf(ang);
}

// ---------------- RoPE apply on q,k; write [BH][T][64] bf16 (q pre-scaled) -------
__global__ __launch_bounds__(256) void rope_qk(const float* __restrict__ qkv,
                                               const float* __restrict__ cosT,
                                               const float* __restrict__ sinT,
                                               u16* __restrict__ Qr,
                                               u16* __restrict__ Kr) {
  int idx = blockIdx.x * 256 + threadIdx.x;   // ((bh*T + t)*32 + j)
  int j = idx & 31;
  int bt = idx >> 5;
  int t = bt & (T_SEQ - 1);
  int bh = bt >> 11;                          // T=2048
  int b = bh >> 4, h = bh & 15;
  float c = cosT[t * 32 + j], s = sinT[t * 32 + j];
  const float* base = qkv + ((size_t)(b * T_SEQ + t)) * 3072 + h * 64 + 2 * j;
  float q1 = base[0],    q2 = base[1];
  float k1 = base[1024], k2 = base[1025];
  size_t o = ((size_t)bh * T_SEQ + t) * 64 + 2 * j;
  Qr[o]     = f2b((q1 * c - q2 * s) * 0.125f);
  Qr[o + 1] = f2b((q2 * c + q1 * s) * 0.125f);
  Kr[o]     = f2b(k1 * c - k2 * s);
  Kr[o + 1] = f2b(k2 * c + k1 * s);
}

// ---------------- V transpose: Vt[bh][d][t] bf16 ----------------
__global__ __launch_bounds__(256) void v_trans(const float* __restrict__ qkv,
                                               u16* __restrict__ Vt) {
  __shared__ u16 tile[64][72];
  int t0 = blockIdx.x * 64;
  int bh = blockIdx.y;
  int b = bh >> 4, h = bh & 15;
  int tid = threadIdx.x;
  #pragma unroll
  for (int i = 0; i < 16; ++i) {
    int c = i * 256 + tid;
    int tr = c >> 6, d = c & 63;
    tile[tr][d] = f2b(qkv[((size_t)(b * T_SEQ + t0 + tr)) * 3072 + 2048 + h * 64 + d]);
  }
  __syncthreads();
  #pragma unroll
  for (int i = 0; i < 16; ++i) {
    int c = i * 256 + tid;
    int d = c >> 6, tc = c & 63;
    Vt[((size_t)bh * 64 + d) * T_SEQ + t0 + tc] = tile[tc][d];
  }
}

// ---------------- GEMM: C[M][ldc] = A[M][K](bf16) * Bt[N][K](bf16)^T (+bias) -----
// 128x128 tile, BK=64, 256 threads (2x2 waves of 64x64), global_load_lds staging.
__global__ __launch_bounds__(256) void gemm_bt(const u16* __restrict__ A,
                                               const u16* __restrict__ Bt,
                                               float* __restrict__ C,
                                               const float* __restrict__ bias,
                                               int K, int ldc) {
  __shared__ u16 As[128 * 64];
  __shared__ u16 Bs[128 * 64];
  const int tid = threadIdx.x;
  const int wid = tid >> 6, lane = tid & 63;
  const int wr = wid >> 1, wc = wid & 1;
  const int col = lane & 15, kq = lane >> 4;
  const int arow0 = blockIdx.x * 128, bcol0 = blockIdx.y * 128;

  f32x4 acc[4][4] = {};

  for (int k0 = 0; k0 < K; k0 += 64) {
    #pragma unroll
    for (int it = 0; it < 4; ++it) {
      int c = it * 256 + tid;
      int r = c >> 3, c8 = (c & 7) << 3;
      gload16(A  + (size_t)(arow0 + r) * K + k0 + c8, (char*)As + c * 16);
      gload16(Bt + (size_t)(bcol0 + r) * K + k0 + c8, (char*)Bs + c * 16);
    }
    asm volatile("s_waitcnt vmcnt(0)" ::: "memory");
    __syncthreads();
    #pragma unroll
    for (int kk = 0; kk < 64; kk += 32) {
      bf16x8 a[4], b[4];
      #pragma unroll
      for (int m = 0; m < 4; ++m)
        a[m] = *(const bf16x8*)(As + (wr * 64 + m * 16 + col) * 64 + kk + kq * 8);
      #pragma unroll
      for (int n = 0; n < 4; ++n)
        b[n] = *(const bf16x8*)(Bs + (wc * 64 + n * 16 + col) * 64 + kk + kq * 8);
      #pragma unroll
      for (int m = 0; m < 4; ++m)
        #pragma unroll
        for (int n = 0; n < 4; ++n)
          acc[m][n] = __builtin_amdgcn_mfma_f32_16x16x32_bf16(a[m], b[n], acc[m][n], 0, 0, 0);
    }
    __syncthreads();
  }

  #pragma unroll
  for (int m = 0; m < 4; ++m)
    #pragma unroll
    for (int n = 0; n < 4; ++n) {
      int cc = bcol0 + wc * 64 + n * 16 + col;
      float bv = bias ? bias[cc] : 0.0f;
      #pragma unroll
      for (int i = 0; i < 4; ++i) {
        int rr = arow0 + wr * 64 + m * 16 + kq * 4 + i;
        C[(size_t)rr * ldc + cc] = acc[m][n][i] + bv;
      }
    }
}

// ---------------- Flash attention (causal), QBLK=64 (4 waves x 16 rows) ----------
__global__ __launch_bounds__(256) void attn_fwd(const u16* __restrict__ Q,
                                                const u16* __restrict__ K,
                                                const u16* __restrict__ V,   // [BH][64][T]
                                                u16* __restrict__ O) {       // [B*T][1024]
  __shared__ u16 Ks[64 * 64];
  __shared__ u16 Vs[64 * 64];
  __shared__ u16 Ps[4][16 * 72];

  const int bh = blockIdx.y;
  const int b = bh >> 4, h = bh & 15;
  const int q0 = blockIdx.x * 64;
  const int tid = threadIdx.x;
  const int wid = tid >> 6, lane = tid & 63;
  const int col = lane & 15, kq = lane >> 4;

  const int qrow = q0 + wid * 16 + col;
  const u16* qp = Q + ((size_t)bh * T_SEQ + qrow) * 64 + kq * 8;
  bf16x8 qa0 = *(const bf16x8*)qp;
  bf16x8 qa1 = *(const bf16x8*)(qp + 32);

  float Mx[4] = {-1e30f, -1e30f, -1e30f, -1e30f};
  float Lx[4] = {0.f, 0.f, 0.f, 0.f};
  f32x4 o_[4] = {};

  const int nkt = blockIdx.x + 1;
  for (int kt = 0; kt < nkt; ++kt) {
    const int kv0 = kt * 64;
    __syncthreads();   // all waves done reading previous K/V tiles
    #pragma unroll
    for (int i = 0; i < 2; ++i) {
      int c = i * 256 + tid;
      int r = c >> 3, c8 = (c & 7) << 3;
      int sw = (r & 7) << 4;
      bf16x8 kv_ = *(const bf16x8*)(K + ((size_t)bh * T_SEQ + kv0 + r) * 64 + c8);
      *(bf16x8*)((char*)Ks + ((r * 128 + c8 * 2) ^ sw)) = kv_;
      bf16x8 vv_ = *(const bf16x8*)(V + ((size_t)bh * 64 + r) * T_SEQ + kv0 + c8);
      *(bf16x8*)((char*)Vs + ((r * 128 + c8 * 2) ^ sw)) = vv_;
    }
    __syncthreads();

    // S = Q K^T  (16 q-rows x 64 keys per wave)
    f32x4 s[4] = {};
    #pragma unroll
    for (int nt = 0; nt < 4; ++nt) {
      int r = nt * 16 + col;
      int sw = (r & 7) << 4;
      bf16x8 kb0 = *(const bf16x8*)((const char*)Ks + ((r * 128 + kq * 16) ^ sw));
      bf16x8 kb1 = *(const bf16x8*)((const char*)Ks + ((r * 128 + 64 + kq * 16) ^ sw));
      s[nt] = __builtin_amdgcn_mfma_f32_16x16x32_bf16(qa0, kb0, s[nt], 0, 0, 0);
      s[nt] = __builtin_amdgcn_mfma_f32_16x16x32_bf16(qa1, kb1, s[nt], 0, 0, 0);
    }

    if (kt == nkt - 1) {  // causal mask: only diagonal tile needs it
      #pragma unroll
      for (int nt = 0; nt < 4; ++nt) {
        int kcol = kv0 + nt * 16 + col;
        #pragma unroll
        for (int i = 0; i < 4; ++i) {
          int rg = q0 + wid * 16 + kq * 4 + i;
          if (kcol > rg) s[nt][i] = -1e30f;
        }
      }
    }

    // online softmax
    float corr[4];
    #pragma unroll
    for (int i = 0; i < 4; ++i) {
      float mx = fmaxf(fmaxf(s[0][i], s[1][i]), fmaxf(s[2][i], s[3][i]));
      #pragma unroll
      for (int d2 = 1; d2 < 16; d2 <<= 1)
        mx = fmaxf(mx, __shfl_xor(mx, d2, 64));
      float mnew = fmaxf(Mx[i], mx);
      corr[i] = __expf(Mx[i] - mnew);
      Mx[i] = mnew;
    }
    float rs[4] = {0.f, 0.f, 0.f, 0.f};
    #pragma unroll
    for (int nt = 0; nt < 4; ++nt)
      #pragma unroll
      for (int i = 0; i < 4; ++i) {
        float p = __expf(s[nt][i] - Mx[i]);
        s[nt][i] = p;
        rs[i] += p;
      }
    #pragma unroll
    for (int i = 0; i < 4; ++i) {
      float t = rs[i];
      #pragma unroll
      for (int d2 = 1; d2 < 16; d2 <<= 1)
        t += __shfl_xor(t, d2, 64);
      Lx[i] = Lx[i] * corr[i] + t;
      #pragma unroll
      for (int nt = 0; nt < 4; ++nt) o_[nt][i] *= corr[i];
    }

    // P -> per-wave LDS (bf16), then read back as MFMA A fragments
    u16* P = &Ps[wid][0];
    #pragma unroll
    for (int nt = 0; nt < 4; ++nt)
      #pragma unroll
      for (int i = 0; i < 4; ++i)
        P[(kq * 4 + i) * 72 + nt * 16 + col] = f2b(s[nt][i]);
    asm volatile("s_waitcnt lgkmcnt(0)" ::: "memory");
    bf16x8 pa0 = *(const bf16x8*)(P + col * 72 + kq * 8);
    bf16x8 pa1 = *(const bf16x8*)(P + col * 72 + 32 + kq * 8);

    // O += P V
    #pragma unroll
    for (int dt = 0; dt < 4; ++dt) {
      int r = dt * 16 + col;
      int sw = (r & 7) << 4;
      bf16x8 vb0 = *(const bf16x8*)((const char*)Vs + ((r * 128 + kq * 16) ^ sw));
      bf16x8 vb1 = *(const bf16x8*)((const char*)Vs + ((r * 128 + 64 + kq * 16) ^ sw));
      o_[dt] = __builtin_amdgcn_mfma_f32_16x16x32_bf16(pa0, vb0, o_[dt], 0, 0, 0);
      o_[dt] = __builtin_amdgcn_mfma_f32_16x16x32_bf16(pa1, vb1, o_[dt], 0, 0, 0);
    }
  }

  #pragma unroll
  for (int dt = 0; dt < 4; ++dt)
    #pragma unroll
    for (int i = 0; i < 4; ++i) {
      int t = q0 + wid * 16 + kq * 4 + i;
      float val = o_[dt][i] / Lx[i];
      O[((size_t)b * T_SEQ + t) * 1024 + h * 64 + dt * 16 + col] = f2b(val);
    }
}

// ---------------- host launch ----------------
extern "C" void kernel_launch(void* const* d_in, const int* in_sizes, int n_in,
                              void* d_out, int out_size, void* d_ws, size_t ws_size,
                              hipStream_t stream) {
  (void)in_sizes; (void)n_in; (void)out_size; (void)ws_size;
  const float* x  = (const float*)d_in[0];
  const float* Wq = (const float*)d_in[1];
  const float* Wk = (const float*)d_in[2];
  const float* Wv = (const float*)d_in[3];
  const float* Wo = (const float*)d_in[4];
  const float* bo = (const float*)d_in[5];
  float* out = (float*)d_out;

  char* ws = (char*)d_ws;
  u16*   xb   = (u16*)(ws);                         //  8 MB
  u16*   Wqkv = (u16*)(ws + (size_t)( 8u << 20));   //  6 MB  [3072][1024] bf16 (= [Wq|Wk|Wv]^T)
  u16*   Wot  = (u16*)(ws + (size_t)(14u << 20));   //  2 MB
  float* qkv  = (float*)(ws + (size_t)(16u << 20)); // 48 MB  [4096][3072] f32
  u16*   Qr   = (u16*)(ws + (size_t)(64u << 20));   //  8 MB  [BH][T][64]
  u16*   Kr   = (u16*)(ws + (size_t)(72u << 20));   //  8 MB
  u16*   Vt   = (u16*)(ws + (size_t)(80u << 20));   //  8 MB  [BH][64][T]
  u16*   Ob   = (u16*)(ws + (size_t)(88u << 20));   //  8 MB  [4096][1024]
  float* cosT = (float*)(ws + (size_t)(96u << 20)); // 256 KB
  float* sinT = (float*)(ws + (size_t)(96u << 20) + (1u << 18));

  // 1. conversions / transposes
  cvt4<<<dim3(MROWS * CDIM / 4 / 256), dim3(256), 0, stream>>>(
      (const float4*)x, (u16x4*)xb, MROWS * CDIM / 4);
  w_trans<<<dim3(16, 16), dim3(256), 0, stream>>>(Wq, Wqkv + (size_t)0 * CDIM * CDIM, CDIM);
  w_trans<<<dim3(16, 16), dim3(256), 0, stream>>>(Wk, Wqkv + (size_t)1 * CDIM * CDIM, CDIM);
  w_trans<<<dim3(16, 16), dim3(256), 0, stream>>>(Wv, Wqkv + (size_t)2 * CDIM * CDIM, CDIM);
  w_trans<<<dim3(16, 16), dim3(256), 0, stream>>>(Wo, Wot, CDIM);
  rope_tab<<<dim3(T_SEQ * 32 / 256), dim3(256), 0, stream>>>(cosT, sinT);

  // 2. fused QKV projection: [4096][1024] x [3072][1024]^T -> f32 [4096][3072]
  gemm_bt<<<dim3(32, 24), dim3(256), 0, stream>>>(xb, Wqkv, qkv, nullptr, CDIM, 3072);

  // 3. RoPE + layout
  rope_qk<<<dim3(BATCH * NH * T_SEQ * 32 / 256), dim3(256), 0, stream>>>(qkv, cosT, sinT, Qr, Kr);
  v_trans<<<dim3(T_SEQ / 64, BATCH * NH), dim3(256), 0, stream>>>(qkv, Vt);

  // 4. attention
  attn_fwd<<<dim3(T_SEQ / 64, BATCH * NH), dim3(256), 0, stream>>>(Qr, Kr, Vt, Ob);

  // 5. output projection + bias -> f32 out
  gemm_bt<<<dim3(32, 8), dim3(256), 0, stream>>>(Ob, Wot, out, bo, CDIM, CDIM);
}

// Round 2
// 196.239 us; speedup vs baseline: 1.1988x; 1.1988x over previous
//
#include <hip/hip_runtime.h>
#include <stdint.h>

// Problem shape (fixed by reference):
#define BATCH 2
#define T_SEQ 2048
#define CDIM  1024
#define NH    16
#define HD    64
#define MROWS (BATCH*T_SEQ)   // 4096

typedef unsigned short u16;
typedef __attribute__((ext_vector_type(8))) short bf16x8;
typedef __attribute__((ext_vector_type(4))) float f32x4;
typedef __attribute__((ext_vector_type(16))) float f32x16;
typedef __attribute__((ext_vector_type(4))) unsigned short u16x4;

__device__ __forceinline__ u16 f2b(float f) {
  union { float f; unsigned int u; } x; x.f = f;
  unsigned int r = x.u + 0x7FFFu + ((x.u >> 16) & 1u);
  return (u16)(r >> 16);
}

__device__ __forceinline__ void gload16(const void* g, void* s) {
  __builtin_amdgcn_global_load_lds(
      (const __attribute__((address_space(1))) void*)g,
      (__attribute__((address_space(3))) void*)s, 16, 0, 0);
}

__device__ __forceinline__ int cvtpk(float lo, float hi_) {
  int w;
  asm("v_cvt_pk_bf16_f32 %0, %1, %2" : "=v"(w) : "v"(lo), "v"(hi_));
  return w;
}

__device__ __forceinline__ bf16x8 mkfrag(int a, int b, int c, int d) {
  union { int i[4]; bf16x8 v; } u;
  u.i[0] = a; u.i[1] = b; u.i[2] = c; u.i[3] = d;
  return u.v;
}

// ---------------- f32 -> bf16 convert (vectorized) ----------------
__global__ __launch_bounds__(256) void cvt4(const float4* __restrict__ in,
                                            u16x4* __restrict__ out, int n4) {
  int i = blockIdx.x * 256 + threadIdx.x;
  if (i < n4) {
    float4 v = in[i];
    u16x4 o = { f2b(v.x), f2b(v.y), f2b(v.z), f2b(v.w) };
    out[i] = o;
  }
}

// ---------------- W transpose + convert: Wt[n][k] = bf16(W[k][n]) ----------------
__global__ __launch_bounds__(256) void w_trans(const float* __restrict__ W,
                                               u16* __restrict__ Wt, int C) {
  __shared__ u16 tile[64][72];
  int k0 = blockIdx.x * 64, n0 = blockIdx.y * 64;
  int tid = threadIdx.x;
  #pragma unroll
  for (int i = 0; i < 16; ++i) {
    int c = i * 256 + tid;
    int kr = c >> 6, nc = c & 63;
    tile[kr][nc] = f2b(W[(size_t)(k0 + kr) * C + n0 + nc]);
  }
  __syncthreads();
  #pragma unroll
  for (int i = 0; i < 16; ++i) {
    int c = i * 256 + tid;
    int nr = c >> 6, kc = c & 63;
    Wt[(size_t)(n0 + nr) * C + k0 + kc] = tile[kc][nr];
  }
}

// ---------------- RoPE cos/sin table ----------------
__global__ __launch_bounds__(256) void rope_tab(float* __restrict__ cosT,
                                                float* __restrict__ sinT) {
  int i = blockIdx.x * 256 + threadIdx.x;   // t*32 + j
  int t = i >> 5, j = i & 31;
  float inv = expf(-(float)j * (9.210340371976184f / 32.0f)); // 10000^(-2j/64)
  float ang = (float)t * inv;
  cosT[i] = cosf(ang);
  sinT[i] = sinf(ang);
}

// ---------------- RoPE apply on q,k; write [BH][T][64] bf16 (q pre-scaled) -------
__global__ __launch_bounds__(256) void rope_qk(const float* __restrict__ qkv,
                                               const float* __restrict__ cosT,
                                               const float* __restrict__ sinT,
                                               u16* __restrict__ Qr,
                                               u16* __restrict__ Kr) {
  int idx = blockIdx.x * 256 + threadIdx.x;   // ((bh*T + t)*32 + j)
  int j = idx & 31;
  int bt = idx >> 5;
  int t = bt & (T_SEQ - 1);
  int bh = bt >> 11;                          // T=2048
  int b = bh >> 4, h = bh & 15;
  float c = cosT[t * 32 + j], s = sinT[t * 32 + j];
  const float* base = qkv + ((size_t)(b * T_SEQ + t)) * 3072 + h * 64 + 2 * j;
  float q1 = base[0],    q2 = base[1];
  float k1 = base[1024], k2 = base[1025];
  size_t o = ((size_t)bh * T_SEQ + t) * 64 + 2 * j;
  Qr[o]     = f2b((q1 * c - q2 * s) * 0.125f);
  Qr[o + 1] = f2b((q2 * c + q1 * s) * 0.125f);
  Kr[o]     = f2b(k1 * c - k2 * s);
  Kr[o + 1] = f2b(k2 * c + k1 * s);
}

// ---------------- V transpose: Vt[bh][d][t] bf16 ----------------
__global__ __launch_bounds__(256) void v_trans(const float* __restrict__ qkv,
                                               u16* __restrict__ Vt) {
  __shared__ u16 tile[64][72];
  int t0 = blockIdx.x * 64;
  int bh = blockIdx.y;
  int b = bh >> 4, h = bh & 15;
  int tid = threadIdx.x;
  #pragma unroll
  for (int i = 0; i < 16; ++i) {
    int c = i * 256 + tid;
    int tr = c >> 6, d = c & 63;
    tile[tr][d] = f2b(qkv[((size_t)(b * T_SEQ + t0 + tr)) * 3072 + 2048 + h * 64 + d]);
  }
  __syncthreads();
  #pragma unroll
  for (int i = 0; i < 16; ++i) {
    int c = i * 256 + tid;
    int d = c >> 6, tc = c & 63;
    Vt[((size_t)bh * 64 + d) * T_SEQ + t0 + tc] = tile[tc][d];
  }
}

// ---------------- GEMM: C[M][ldc] = A[M][K](bf16) * Bt[N][K](bf16)^T (+bias) -----
__global__ __launch_bounds__(256) void gemm_bt(const u16* __restrict__ A,
                                               const u16* __restrict__ Bt,
                                               float* __restrict__ C,
                                               const float* __restrict__ bias,
                                               int K, int ldc) {
  __shared__ u16 As[128 * 64];
  __shared__ u16 Bs[128 * 64];
  const int tid = threadIdx.x;
  const int wid = tid >> 6, lane = tid & 63;
  const int wr = wid >> 1, wc = wid & 1;
  const int col = lane & 15, kq = lane >> 4;
  const int arow0 = blockIdx.x * 128, bcol0 = blockIdx.y * 128;

  f32x4 acc[4][4] = {};

  for (int k0 = 0; k0 < K; k0 += 64) {
    #pragma unroll
    for (int it = 0; it < 4; ++it) {
      int c = it * 256 + tid;
      int r = c >> 3, c8 = (c & 7) << 3;
      gload16(A  + (size_t)(arow0 + r) * K + k0 + c8, (char*)As + c * 16);
      gload16(Bt + (size_t)(bcol0 + r) * K + k0 + c8, (char*)Bs + c * 16);
    }
    asm volatile("s_waitcnt vmcnt(0)" ::: "memory");
    __syncthreads();
    #pragma unroll
    for (int kk = 0; kk < 64; kk += 32) {
      bf16x8 a[4], b[4];
      #pragma unroll
      for (int m = 0; m < 4; ++m)
        a[m] = *(const bf16x8*)(As + (wr * 64 + m * 16 + col) * 64 + kk + kq * 8);
      #pragma unroll
      for (int n = 0; n < 4; ++n)
        b[n] = *(const bf16x8*)(Bs + (wc * 64 + n * 16 + col) * 64 + kk + kq * 8);
      #pragma unroll
      for (int m = 0; m < 4; ++m)
        #pragma unroll
        for (int n = 0; n < 4; ++n)
          acc[m][n] = __builtin_amdgcn_mfma_f32_16x16x32_bf16(a[m], b[n], acc[m][n], 0, 0, 0);
    }
    __syncthreads();
  }

  #pragma unroll
  for (int m = 0; m < 4; ++m)
    #pragma unroll
    for (int n = 0; n < 4; ++n) {
      int cc = bcol0 + wc * 64 + n * 16 + col;
      float bv = bias ? bias[cc] : 0.0f;
      #pragma unroll
      for (int i = 0; i < 4; ++i) {
        int rr = arow0 + wr * 64 + m * 16 + kq * 4 + i;
        C[(size_t)rr * ldc + cc] = acc[m][n][i] + bv;
      }
    }
}

// ---------------- Flash attention v2: 4 waves x 32 q-rows, swapped-operand 32x32 -
// S^T = mfma(K, Q): lane holds S[k=crow(r,hi)][q=lane&31]  -> softmax lane-local
// O^T = mfma(V^T, P^T): lane holds O[d=32dt+crow(r,hi)][q=lane&31]
__global__ __launch_bounds__(256) void attn_fwd2(const u16* __restrict__ Q,
                                                 const u16* __restrict__ K,
                                                 const u16* __restrict__ V,  // [BH][64][T]
                                                 u16* __restrict__ O) {      // [B*T][1024]
  __shared__ __align__(16) char smem[18432];
  u16* Ks = (u16*)smem;                 // [64][64] bf16, XOR-swizzled
  u16* Vs = (u16*)(smem + 8192);        // V^T tile [64 d][64 k], XOR-swizzled

  const int bh = blockIdx.y;
  const int b = bh >> 4, h = bh & 15;
  const int qc = 15 - blockIdx.x;       // longest blocks dispatched first
  const int q0 = qc * 128;
  const int tid = threadIdx.x;
  const int wid = tid >> 6, lane = tid & 63;
  const int l31 = lane & 31, hi = lane >> 5;
  const int wq0 = q0 + wid * 32;
  const int qrow = wq0 + l31;

  // Q fragments: qa[dk] holds Q[q=l31][d = 16*dk + 8*hi + j]
  bf16x8 qa[4];
  const u16* qbase = Q + ((size_t)bh * T_SEQ + qrow) * 64 + hi * 8;
  #pragma unroll
  for (int dk = 0; dk < 4; ++dk)
    qa[dk] = *(const bf16x8*)(qbase + dk * 16);

  float M = -1e30f, L = 0.f;
  f32x16 ot0 = {}, ot1 = {};

  const int nkt = 2 * qc + 2;
  const int sr = tid >> 3;            // staging row 0..31
  const int sc = (tid & 7) * 8;       // staging col (elements)

  for (int kt = 0; kt < nkt; ++kt) {
    const int kv0 = kt * 64;
    __syncthreads();
    #pragma unroll
    for (int it = 0; it < 2; ++it) {
      int r = sr + it * 32;
      int sw = (r & 7) << 4;
      bf16x8 kreg = *(const bf16x8*)(K + ((size_t)bh * T_SEQ + kv0 + r) * 64 + sc);
      *(bf16x8*)((char*)Ks + ((r * 128 + sc * 2) ^ sw)) = kreg;
      bf16x8 vreg = *(const bf16x8*)(V + ((size_t)bh * 64 + r) * T_SEQ + kv0 + sc);
      *(bf16x8*)((char*)Vs + ((r * 128 + sc * 2) ^ sw)) = vreg;
    }
    __syncthreads();
    if (kv0 > wq0 + 31) continue;     // fully masked for this warp (wave-uniform)

    // ---- S^T = K . Q^T : two 32x32 outputs (k-halves), accumulate over d ----
    f32x16 st0 = {}, st1 = {};
    #pragma unroll
    for (int dk = 0; dk < 4; ++dk) {
      int sw = (l31 & 7) << 4;
      bf16x8 ka0 = *(const bf16x8*)((char*)Ks + ((l31 * 128 + dk * 32 + hi * 16) ^ sw));
      bf16x8 ka1 = *(const bf16x8*)((char*)Ks + (((l31 + 32) * 128 + dk * 32 + hi * 16) ^ sw));
      st0 = __builtin_amdgcn_mfma_f32_32x32x16_bf16(ka0, qa[dk], st0, 0, 0, 0);
      st1 = __builtin_amdgcn_mfma_f32_32x32x16_bf16(ka1, qa[dk], st1, 0, 0, 0);
    }

    // ---- causal mask (diagonal region only) ----
    if (kv0 + 63 > wq0) {
      #pragma unroll
      for (int r = 0; r < 16; ++r) {
        int kl = (r & 3) + 8 * (r >> 2) + 4 * hi;
        if (kv0 + kl > qrow)      st0[r] = -1e30f;
        if (kv0 + 32 + kl > qrow) st1[r] = -1e30f;
      }
    }

    // ---- online softmax (lane-local rows) ----
    float t0 = fmaxf(st0[0], st1[0]), t1 = fmaxf(st0[1], st1[1]);
    float t2 = fmaxf(st0[2], st1[2]), t3 = fmaxf(st0[3], st1[3]);
    #pragma unroll
    for (int r = 4; r < 16; r += 4) {
      t0 = fmaxf(t0, fmaxf(st0[r],     st1[r]));
      t1 = fmaxf(t1, fmaxf(st0[r + 1], st1[r + 1]));
      t2 = fmaxf(t2, fmaxf(st0[r + 2], st1[r + 2]));
      t3 = fmaxf(t3, fmaxf(st0[r + 3], st1[r + 3]));
    }
    float mx = fmaxf(fmaxf(t0, t1), fmaxf(t2, t3));
    mx = fmaxf(mx, __shfl_xor(mx, 32, 64));
    float Mn = fmaxf(M, mx);
    float corr = __expf(M - Mn);
    M = Mn;

    float s0 = 0.f, s1 = 0.f, s2 = 0.f, s3 = 0.f;
    #pragma unroll
    for (int r = 0; r < 16; r += 4) {
      st0[r]     = __expf(st0[r]     - M); st1[r]     = __expf(st1[r]     - M);
      st0[r + 1] = __expf(st0[r + 1] - M); st1[r + 1] = __expf(st1[r + 1] - M);
      st0[r + 2] = __expf(st0[r + 2] - M); st1[r + 2] = __expf(st1[r + 2] - M);
      st0[r + 3] = __expf(st0[r + 3] - M); st1[r + 3] = __expf(st1[r + 3] - M);
      s0 += st0[r]     + st1[r];
      s1 += st0[r + 1] + st1[r + 1];
      s2 += st0[r + 2] + st1[r + 2];
      s3 += st0[r + 3] + st1[r + 3];
    }
    float sum = (s0 + s1) + (s2 + s3);
    sum += __shfl_xor(sum, 32, 64);
    L = L * corr + sum;
    ot0 *= corr;
    ot1 *= corr;

    // ---- P^T -> bf16 B-fragments via cvt_pk + permlane32_swap (natural k-order) -
    int x0 = cvtpk(st0[0], st0[1]),   y0 = cvtpk(st0[4], st0[5]);
    int x1 = cvtpk(st0[2], st0[3]),   y1 = cvtpk(st0[6], st0[7]);
    int x2 = cvtpk(st0[8], st0[9]),   y2 = cvtpk(st0[12], st0[13]);
    int x3 = cvtpk(st0[10], st0[11]), y3 = cvtpk(st0[14], st0[15]);
    asm("v_permlane32_swap_b32 %0, %1" : "+v"(x0), "+v"(y0));
    asm("v_permlane32_swap_b32 %0, %1" : "+v"(x1), "+v"(y1));
    asm("v_permlane32_swap_b32 %0, %1" : "+v"(x2), "+v"(y2));
    asm("v_permlane32_swap_b32 %0, %1" : "+v"(x3), "+v"(y3));
    int z0 = cvtpk(st1[0], st1[1]),   w0 = cvtpk(st1[4], st1[5]);
    int z1 = cvtpk(st1[2], st1[3]),   w1 = cvtpk(st1[6], st1[7]);
    int z2 = cvtpk(st1[8], st1[9]),   w2 = cvtpk(st1[12], st1[13]);
    int z3 = cvtpk(st1[10], st1[11]), w3 = cvtpk(st1[14], st1[15]);
    asm("v_permlane32_swap_b32 %0, %1" : "+v"(z0), "+v"(w0));
    asm("v_permlane32_swap_b32 %0, %1" : "+v"(z1), "+v"(w1));
    asm("v_permlane32_swap_b32 %0, %1" : "+v"(z2), "+v"(w2));
    asm("v_permlane32_swap_b32 %0, %1" : "+v"(z3), "+v"(w3));
    bf16x8 pb[4];
    pb[0] = mkfrag(x0, x1, y0, y1);   // k  0..15
    pb[1] = mkfrag(x2, x3, y2, y3);   // k 16..31
    pb[2] = mkfrag(z0, z1, w0, w1);   // k 32..47
    pb[3] = mkfrag(z2, z3, w2, w3);   // k 48..63

    // ---- O^T += V^T . P^T ----
    #pragma unroll
    for (int ks = 0; ks < 4; ++ks) {
      int sw = (l31 & 7) << 4;
      bf16x8 va0 = *(const bf16x8*)((char*)Vs + ((l31 * 128 + ks * 32 + hi * 16) ^ sw));
      bf16x8 va1 = *(const bf16x8*)((char*)Vs + (((l31 + 32) * 128 + ks * 32 + hi * 16) ^ sw));
      ot0 = __builtin_amdgcn_mfma_f32_32x32x16_bf16(va0, pb[ks], ot0, 0, 0, 0);
      ot1 = __builtin_amdgcn_mfma_f32_32x32x16_bf16(va1, pb[ks], ot1, 0, 0, 0);
    }
  }

  // ---- epilogue: transpose O^T -> O via per-warp LDS, coalesced store ----
  __syncthreads();   // staging buffers no longer needed; alias per-warp regions
  char* ep = smem + wid * 4608;        // [32 q][72 d] u16, row stride 144B
  float invL = 1.0f / L;
  #pragma unroll
  for (int r = 0; r < 16; r += 2) {
    int d0_ = (r & 3) + 8 * (r >> 2) + 4 * hi;   // even
    int wA = cvtpk(ot0[r] * invL, ot0[r + 1] * invL);
    *(int*)(ep + l31 * 144 + d0_ * 2) = wA;
    int wB = cvtpk(ot1[r] * invL, ot1[r + 1] * invL);
    *(int*)(ep + l31 * 144 + (32 + d0_) * 2) = wB;
  }
  asm volatile("s_waitcnt lgkmcnt(0)" ::: "memory");
  #pragma unroll
  for (int pass = 0; pass < 4; ++pass) {
    int qr = pass * 8 + (lane >> 3);
    bf16x8 val = *(const bf16x8*)(ep + qr * 144 + (lane & 7) * 16);
    int t = wq0 + qr;
    *(bf16x8*)(O + ((size_t)(b * T_SEQ + t)) * 1024 + h * 64 + (lane & 7) * 8) = val;
  }
}

// ---------------- host launch ----------------
extern "C" void kernel_launch(void* const* d_in, const int* in_sizes, int n_in,
                              void* d_out, int out_size, void* d_ws, size_t ws_size,
                              hipStream_t stream) {
  (void)in_sizes; (void)n_in; (void)out_size; (void)ws_size;
  const float* x  = (const float*)d_in[0];
  const float* Wq = (const float*)d_in[1];
  const float* Wk = (const float*)d_in[2];
  const float* Wv = (const float*)d_in[3];
  const float* Wo = (const float*)d_in[4];
  const float* bo = (const float*)d_in[5];
  float* out = (float*)d_out;

  char* ws = (char*)d_ws;
  u16*   xb   = (u16*)(ws);                         //  8 MB
  u16*   Wqkv = (u16*)(ws + (size_t)( 8u << 20));   //  6 MB  [3072][1024] bf16
  u16*   Wot  = (u16*)(ws + (size_t)(14u << 20));   //  2 MB
  float* qkv  = (float*)(ws + (size_t)(16u << 20)); // 48 MB  [4096][3072] f32
  u16*   Qr   = (u16*)(ws + (size_t)(64u << 20));   //  8 MB  [BH][T][64]
  u16*   Kr   = (u16*)(ws + (size_t)(72u << 20));   //  8 MB
  u16*   Vt   = (u16*)(ws + (size_t)(80u << 20));   //  8 MB  [BH][64][T]
  u16*   Ob   = (u16*)(ws + (size_t)(88u << 20));   //  8 MB  [4096][1024]
  float* cosT = (float*)(ws + (size_t)(96u << 20)); // 256 KB
  float* sinT = (float*)(ws + (size_t)(96u << 20) + (1u << 18));

  cvt4<<<dim3(MROWS * CDIM / 4 / 256), dim3(256), 0, stream>>>(
      (const float4*)x, (u16x4*)xb, MROWS * CDIM / 4);
  w_trans<<<dim3(16, 16), dim3(256), 0, stream>>>(Wq, Wqkv + (size_t)0 * CDIM * CDIM, CDIM);
  w_trans<<<dim3(16, 16), dim3(256), 0, stream>>>(Wk, Wqkv + (size_t)1 * CDIM * CDIM, CDIM);
  w_trans<<<dim3(16, 16), dim3(256), 0, stream>>>(Wv, Wqkv + (size_t)2 * CDIM * CDIM, CDIM);
  w_trans<<<dim3(16, 16), dim3(256), 0, stream>>>(Wo, Wot, CDIM);
  rope_tab<<<dim3(T_SEQ * 32 / 256), dim3(256), 0, stream>>>(cosT, sinT);

  gemm_bt<<<dim3(32, 24), dim3(256), 0, stream>>>(xb, Wqkv, qkv, nullptr, CDIM, 3072);

  rope_qk<<<dim3(BATCH * NH * T_SEQ * 32 / 256), dim3(256), 0, stream>>>(qkv, cosT, sinT, Qr, Kr);
  v_trans<<<dim3(T_SEQ / 64, BATCH * NH), dim3(256), 0, stream>>>(qkv, Vt);

  attn_fwd2<<<dim3(16, 32), dim3(256), 0, stream>>>(Qr, Kr, Vt, Ob);

  gemm_bt<<<dim3(32, 8), dim3(256), 0, stream>>>(Ob, Wot, out, bo, CDIM, CDIM);
}